// Round 5
// baseline (201.527 us; speedup 1.0000x reference)
//
#include <hip/hip_runtime.h>
#include <hip/hip_fp16.h>

#define NC_MEM 64
#define NC_IMG 64
#define NC     128
#define B_     32
#define H_     64
#define W_     96
#define HW_    (H_ * W_)      // 6144
#define P_TILE 128
#define NTILES (HW_ / P_TILE) // 48
#define T_BLK  2              // pixel-tiles per block (pipelined)
#define FS     520            // frag stride in ushorts: 512 + 8 pad
#define FOFF(pt, ks) ((((pt) * 4) + (ks)) * FS)
// rotated block placement (conflict-free staging writes, see v4 notes)
#define XOFF(pt, ks, blk) (FOFF(pt, ks) + ((((blk) + (pt)) & 63) << 3))

// d_ws byte layout
#define WA_HI  0                       // ushort[3][8][4][64][8] (f16 hi, A-frag order)
#define WA_LO  98304                   // f16 lo (w - f16(w))
#define XF_OFF 196608                  // float[32][16]
#define UM_OFF 198656                  // float[32]

typedef _Float16 f16x8 __attribute__((ext_vector_type(8)));
typedef __attribute__((ext_vector_type(4))) float f32x4;

__device__ inline unsigned pk2h(float a, float b) {
    __half2 h = __floats2half2_rn(a, b);
    return *(const unsigned*)&h;
}

// LDS-only barrier: orders ds ops (lgkmcnt) across the workgroup WITHOUT
// draining vmcnt. __syncthreads() emits s_waitcnt vmcnt(0) before s_barrier,
// which kills every in-flight global load (W prefetch, next-tile stage) --
// v2/v4 evidence: 2 vs 4 blocks/CU and 3 vs 5 barriers both changed nothing;
// the invariant cost is this drain-induced phase serialization.
// Memory-clobber asm on both flanks + sched_barrier(0) pins all LDS ops to
// their side of the barrier (rule 18).
__device__ inline void bar_lds() {
    __builtin_amdgcn_sched_barrier(0);
    asm volatile("s_waitcnt lgkmcnt(0)" ::: "memory");
    __builtin_amdgcn_s_barrier();
    asm volatile("" ::: "memory");
    __builtin_amdgcn_sched_barrier(0);
}

// ---------------------------------------------------------------------------
// prep: blocks 0..191 split W into f16 hi/lo in MFMA A-fragment order;
// block 192 computes xf via adjugate inverse + decodes use_memory.
// ---------------------------------------------------------------------------
__global__ void prep(const float* __restrict__ Ws,
                     const float* __restrict__ prev_ext,
                     const float* __restrict__ cur_ext,
                     const int* __restrict__ mem_idx,
                     const unsigned char* __restrict__ um_raw,
                     unsigned char* __restrict__ wsb) {
    if (blockIdx.x < 192) {
        int idx = blockIdx.x * 256 + threadIdx.x;   // < 49152 = 3*128*128
        int l = idx >> 14, r = idx & 16383, o = r >> 7, c = r & 127;
        float w = Ws[idx];
        __half hi = __float2half_rn(w);
        __half lo = __float2half_rn(w - __half2float(hi));
        int mt = o >> 4, lm = o & 15, ks = c >> 5, kr = c & 31, q = kr >> 3, j = kr & 7;
        int lane = q * 16 + lm;
        int di = ((((l * 8 + mt) * 4 + ks) * 64 + lane) << 3) + j;
        ((unsigned short*)(wsb + WA_HI))[di] = __half_as_ushort(hi);
        ((unsigned short*)(wsb + WA_LO))[di] = __half_as_ushort(lo);
        return;
    }
    int tb = threadIdx.x;
    if (tb >= 64) return;
    bool flag = (tb < 32) && (tb & 3) && (um_raw[tb] != 0);
    bool is_bool = __any(flag);
    if (tb >= B_) return;
    int b = tb;
    bool um = is_bool ? (um_raw[b] != 0) : (((const int*)um_raw)[b] != 0);
    int mi = mem_idx[b];

    float a[16];
#pragma unroll
    for (int i = 0; i < 16; ++i)
        a[i] = um ? prev_ext[mi * 16 + i] : ((i % 5 == 0) ? 1.f : 0.f);

    float s0 = a[0]*a[5]  - a[1]*a[4];
    float s1 = a[0]*a[6]  - a[2]*a[4];
    float s2 = a[0]*a[7]  - a[3]*a[4];
    float s3 = a[1]*a[6]  - a[2]*a[5];
    float s4 = a[1]*a[7]  - a[3]*a[5];
    float s5 = a[2]*a[7]  - a[3]*a[6];
    float c5 = a[10]*a[15] - a[11]*a[14];
    float c4 = a[9]*a[15]  - a[11]*a[13];
    float c3 = a[9]*a[14]  - a[10]*a[13];
    float c2 = a[8]*a[15]  - a[11]*a[12];
    float c1 = a[8]*a[14]  - a[10]*a[12];
    float c0 = a[8]*a[13]  - a[9]*a[12];
    float det = s0*c5 - s1*c4 + s2*c3 + s3*c2 - s4*c1 + s5*c0;
    float id = 1.0f / det;

    float inv[16];
    inv[0]  = ( a[5]*c5  - a[6]*c4  + a[7]*c3)  * id;
    inv[1]  = (-a[1]*c5  + a[2]*c4  - a[3]*c3)  * id;
    inv[2]  = ( a[13]*s5 - a[14]*s4 + a[15]*s3) * id;
    inv[3]  = (-a[9]*s5  + a[10]*s4 - a[11]*s3) * id;
    inv[4]  = (-a[4]*c5  + a[6]*c2  - a[7]*c1)  * id;
    inv[5]  = ( a[0]*c5  - a[2]*c2  + a[3]*c1)  * id;
    inv[6]  = (-a[12]*s5 + a[14]*s2 - a[15]*s1) * id;
    inv[7]  = ( a[8]*s5  - a[10]*s2 + a[11]*s1) * id;
    inv[8]  = ( a[4]*c4  - a[5]*c2  + a[7]*c0)  * id;
    inv[9]  = (-a[0]*c4  + a[1]*c2  - a[3]*c0)  * id;
    inv[10] = ( a[12]*s4 - a[13]*s2 + a[15]*s0) * id;
    inv[11] = (-a[8]*s4  + a[9]*s2  - a[11]*s0) * id;
    inv[12] = (-a[4]*c3  + a[5]*c1  - a[6]*c0)  * id;
    inv[13] = ( a[0]*c3  - a[1]*c1  + a[2]*c0)  * id;
    inv[14] = (-a[12]*s3 + a[13]*s1 - a[14]*s0) * id;
    inv[15] = ( a[8]*s3  - a[9]*s1  + a[10]*s0) * id;

    float* xf = (float*)(wsb + XF_OFF) + b * 16;
#pragma unroll
    for (int i = 0; i < 4; ++i)
#pragma unroll
        for (int j2 = 0; j2 < 4; ++j2) {
            float s = 0.f;
#pragma unroll
            for (int k = 0; k < 4; ++k)
                s += cur_ext[b * 16 + i * 4 + k] * inv[k * 4 + j2];
            xf[i * 4 + j2] = s;
        }
    ((float*)(wsb + UM_OFF))[b] = um ? 1.f : 0.f;
}

// ---------------------------------------------------------------------------
// fused_main v5: lgkm-only barriers (global loads/stores survive barriers) +
// 2-tile-per-block pipeline: tile t+1's global loads issue at the top of
// tile t's compute (~2 layers of latency cover), packed into the other LDS
// buffer after L1 with no extra sync. W fragments reload per tile through a
// laundered base (blocks GVN cross-tile CSE -> bounded VGPR). Numerics
// bit-identical to v4 (same load/FTL/pack/MFMA order).
// ---------------------------------------------------------------------------
__global__ __launch_bounds__(512, 4)
void fused_main(const float* __restrict__ img, const float* __restrict__ mem,
                const int* __restrict__ mem_idx, const float* __restrict__ bs,
                const unsigned char* __restrict__ wsb, float* __restrict__ out) {
    __shared__ unsigned short xh[2][32 * FS]; // 2 x 33280 B ping-pong

    const int t    = threadIdx.x;
    const int b    = blockIdx.y;
    const int hw00 = blockIdx.x * (P_TILE * T_BLK);
    const bool umb = ((const float*)(wsb + UM_OFF))[b] != 0.f;
    const int mi   = mem_idx[b];

    const f16x8* __restrict__ WH = (const f16x8*)(wsb + WA_HI);
    const f16x8* __restrict__ WL = (const f16x8*)(wsb + WA_LO);

    const int w    = t >> 6;
    const int lane = t & 63;
    const int wq   = lane >> 4;
    const int lm   = lane & 15;
    const int mt0  = 2 * (w & 3);
    const int nt0  = 4 * (w >> 2);
    const int mt2  = 4 + (w & 3);

    // staging thread mapping (v4 lane remap: conflict-free b128 writes)
    const int q   = ((t & 7) << 2) | ((t >> 3) & 3); // px quad
    const int og  = t >> 5;                          // 0..15
    const int pt  = q >> 2;                          // == t & 7

    auto stage_load = [&](int hw0t, f32x4* v) {
        const int px0 = hw0t + q * 4;
        if (umb) {
            const int c0 = og * 8;
            const float* basep = (c0 < NC_MEM)
                ? (mem + ((size_t)mi * NC_MEM + c0) * HW_ + px0)
                : (img + ((size_t)b * NC_IMG + (c0 - NC_MEM)) * HW_ + px0);
#pragma unroll
            for (int cc = 0; cc < 8; ++cc)
                v[cc] = *(const f32x4*)(basep + (size_t)cc * HW_);
        } else {
            const int c0 = og * 4;  // img channels only
#pragma unroll
            for (int cc = 0; cc < 4; ++cc)
                v[cc] = *(const f32x4*)(img + ((size_t)b * NC_IMG + c0 + cc) * HW_ + px0);
        }
    };

    auto stage_write = [&](unsigned short* xb, f32x4* v) {
        if (umb) {
            if (og < 4) {              // FTL on channel groups 0..7 (c < 32)
                float xfv[16];
                const float* xfp = (const float*)(wsb + XF_OFF) + b * 16;
#pragma unroll
                for (int j = 0; j < 4; ++j)
                    *(f32x4*)&xfv[j * 4] = *(const f32x4*)&xfp[j * 4];
#pragma unroll
                for (int sg = 0; sg < 2; ++sg) {
#pragma unroll
                    for (int i = 0; i < 4; ++i) {
                        float a0 = v[4*sg+0][i], a1 = v[4*sg+1][i];
                        float a2 = v[4*sg+2][i], a3 = v[4*sg+3][i];
                        v[4*sg+0][i] = xfv[0]*a0  + xfv[1]*a1  + xfv[2]*a2  + xfv[3]*a3;
                        v[4*sg+1][i] = xfv[4]*a0  + xfv[5]*a1  + xfv[6]*a2  + xfv[7]*a3;
                        v[4*sg+2][i] = xfv[8]*a0  + xfv[9]*a1  + xfv[10]*a2 + xfv[11]*a3;
                        v[4*sg+3][i] = xfv[12]*a0 + xfv[13]*a1 + xfv[14]*a2 + xfv[15]*a3;
                    }
                }
            }
            const int bk0 = (og & 3) * 16 + (q & 3) * 4;
#pragma unroll
            for (int i = 0; i < 4; ++i) {
                uint4 pk;
                pk.x = pk2h(v[0][i], v[1][i]);
                pk.y = pk2h(v[2][i], v[3][i]);
                pk.z = pk2h(v[4][i], v[5][i]);
                pk.w = pk2h(v[6][i], v[7][i]);
                *(uint4*)&xb[XOFF(pt, og >> 2, bk0 + i)] = pk;
            }
        } else {
            const int gg = 16 + og;
            const int bk0 = ((gg & 7) >> 1) * 16 + (q & 3) * 4;
            const int hoff = (gg & 1) * 4;
#pragma unroll
            for (int i = 0; i < 4; ++i)
                *(uint2*)&xb[XOFF(pt, gg >> 3, bk0 + i) + hoff] =
                    make_uint2(pk2h(v[0][i], v[1][i]), pk2h(v[2][i], v[3][i]));
        }
    };

    auto run_ks_f = [&](const unsigned short* xc, int ks,
                        f16x8 ah0, f16x8 al0, f16x8 ah1, f16x8 al1,
                        f32x4 (&ac)[2][4]) {
#pragma unroll
        for (int nt = 0; nt < 4; ++nt) {
            f16x8 bh = *(const f16x8*)&xc[XOFF(nt0 + nt, ks, lane)];
            ac[0][nt] = __builtin_amdgcn_mfma_f32_16x16x32_f16(ah0, bh, ac[0][nt], 0, 0, 0);
            ac[1][nt] = __builtin_amdgcn_mfma_f32_16x16x32_f16(ah1, bh, ac[1][nt], 0, 0, 0);
            ac[0][nt] = __builtin_amdgcn_mfma_f32_16x16x32_f16(al0, bh, ac[0][nt], 0, 0, 0);
            ac[1][nt] = __builtin_amdgcn_mfma_f32_16x16x32_f16(al1, bh, ac[1][nt], 0, 0, 0);
        }
    };
    auto run_ks = [&](const unsigned short* xc, const f16x8* WHt, const f16x8* WLt,
                      int l, int ks, f32x4 (&ac)[2][4]) {
        int f0 = ((l * 8 + mt0) * 4 + ks) * 64 + lane;
        int f1 = f0 + 256;
        run_ks_f(xc, ks, WHt[f0], WLt[f0], WHt[f1], WLt[f1], ac);
    };
    auto writeback = [&](unsigned short* xb, f32x4 (&ac)[2][4]) {
#pragma unroll
        for (int mi2 = 0; mi2 < 2; ++mi2) {
            const int mt = mt0 + mi2;
            const int ks2 = mt >> 1;
            const int lane_f = ((mt & 1) * 2 + (wq >> 1)) * 16 + lm;
            const int j0 = (wq & 1) * 4;
#pragma unroll
            for (int nt = 0; nt < 4; ++nt) {
                float v0 = fmaxf(ac[mi2][nt][0], 0.f);
                float v1 = fmaxf(ac[mi2][nt][1], 0.f);
                float v2 = fmaxf(ac[mi2][nt][2], 0.f);
                float v3 = fmaxf(ac[mi2][nt][3], 0.f);
                *(uint2*)&xb[XOFF(nt0 + nt, ks2, lane_f) + j0] =
                    make_uint2(pk2h(v0, v1), pk2h(v2, v3));
            }
        }
    };

    // ---- prologue: stage tile 0 into xh[0]; prefetch tile0-L0 W frags ----
    const int kpa = umb ? 0 : 2, kpb = umb ? 1 : 3;
    {
        f32x4 v0[8];
        stage_load(hw00, v0);
        stage_write(xh[0], v0);
    }
    f16x8 pa_h, pa_l, pb_h, pb_l, pc_h, pc_l, pd_h, pd_l; // next-L0 frags
    {
        int f0 = (mt0 * 4 + kpa) * 64 + lane, f1 = f0 + 256;
        pa_h = WH[f0]; pa_l = WL[f0]; pb_h = WH[f1]; pb_l = WL[f1];
        int g0 = (mt0 * 4 + kpb) * 64 + lane, g1 = g0 + 256;
        pc_h = WH[g0]; pc_l = WL[g0]; pd_h = WH[g1]; pd_l = WL[g1];
    }
    bar_lds();  // B1: tile0 staged

#pragma unroll
    for (int tt = 0; tt < T_BLK; ++tt) {
        unsigned short* xc = xh[tt];
        unsigned short* xn = xh[tt ^ 1];
        const int hw0t = hw00 + tt * P_TILE;

        // laundered zero offset: blocks GVN from CSE-ing W/bias loads across
        // tiles (would pin 100+ VGPRs of identical fragments)
        unsigned zo = 0;
        asm volatile("" : "+s"(zo));
        const f16x8* WHt = WH + zo;
        const f16x8* WLt = WL + zo;
        const float* bst = bs + zo;

        // issue next tile's global loads NOW; they stay in flight across the
        // lgkm-only barriers and land during L0+L1 compute
        f32x4 vn[8];
        if (tt + 1 < T_BLK) stage_load(hw0t + P_TILE, vn);

        f32x4 acc[2][4];
        // ---------------- layer 0 ----------------
#pragma unroll
        for (int mi2 = 0; mi2 < 2; ++mi2) {
            f32x4 bv = *(const f32x4*)&bst[0 * NC + (mt0 + mi2) * 16 + wq * 4];
#pragma unroll
            for (int nt = 0; nt < 4; ++nt) acc[mi2][nt] = bv;
        }
        __builtin_amdgcn_s_setprio(1);
        run_ks_f(xc, kpa, pa_h, pa_l, pb_h, pb_l, acc);
        run_ks_f(xc, kpb, pc_h, pc_l, pd_h, pd_l, acc);
        if (umb) {
            run_ks(xc, WHt, WLt, 0, 2, acc);
            run_ks(xc, WHt, WLt, 0, 3, acc);
        }
        __builtin_amdgcn_s_setprio(0);
        bar_lds();              // B2: L0 reads of xc done
        writeback(xc, acc);
        bar_lds();              // B3: L0 output visible

        // ---------------- layer 1 ----------------
#pragma unroll
        for (int mi2 = 0; mi2 < 2; ++mi2) {
            f32x4 bv = *(const f32x4*)&bst[1 * NC + (mt0 + mi2) * 16 + wq * 4];
#pragma unroll
            for (int nt = 0; nt < 4; ++nt) acc[mi2][nt] = bv;
        }
        __builtin_amdgcn_s_setprio(1);
        run_ks(xc, WHt, WLt, 1, 0, acc);
        run_ks(xc, WHt, WLt, 1, 1, acc);
        run_ks(xc, WHt, WLt, 1, 2, acc);
        run_ks(xc, WHt, WLt, 1, 3, acc);
        __builtin_amdgcn_s_setprio(0);
        // next tile's loads have landed by now: FTL + pack into the OTHER
        // buffer (no barrier needed -- xn untouched by current tile)
        if (tt + 1 < T_BLK) stage_write(xn, vn);
        bar_lds();              // B4: L1 reads done + stage writes complete
        writeback(xc, acc);
        bar_lds();              // B5: L1 output visible

        // ---------------- layer 2: out channels 64..127 ----------------
        {
            f32x4 a2[4];
            f32x4 bv = *(const f32x4*)&bst[2 * NC + mt2 * 16 + wq * 4];
#pragma unroll
            for (int nt = 0; nt < 4; ++nt) a2[nt] = bv;
            __builtin_amdgcn_s_setprio(1);
#pragma unroll
            for (int ks = 0; ks < 4; ++ks) {
                int f = ((2 * 8 + mt2) * 4 + ks) * 64 + lane;
                f16x8 ah = WHt[f], al = WLt[f];
#pragma unroll
                for (int nt = 0; nt < 4; ++nt) {
                    f16x8 bh = *(const f16x8*)&xc[XOFF(nt0 + nt, ks, lane)];
                    a2[nt] = __builtin_amdgcn_mfma_f32_16x16x32_f16(ah, bh, a2[nt], 0, 0, 0);
                    a2[nt] = __builtin_amdgcn_mfma_f32_16x16x32_f16(al, bh, a2[nt], 0, 0, 0);
                }
            }
            __builtin_amdgcn_s_setprio(0);
            const int oc0 = mt2 * 16 + wq * 4 - 64; // 0..63
#pragma unroll
            for (int nt = 0; nt < 4; ++nt) {
                float* dst = out + ((size_t)b * 64 + oc0) * HW_ + hw0t + (nt0 + nt) * 16 + lm;
#pragma unroll
                for (int r = 0; r < 4; ++r)
                    __builtin_nontemporal_store(a2[nt][r], dst + (size_t)r * HW_);
            }
        }
        if (tt + 1 < T_BLK) {
            // reload next-tile L0 frags (laundered base -> real reload, small
            // live range across the tile boundary)
            int f0 = (mt0 * 4 + kpa) * 64 + lane, f1 = f0 + 256;
            pa_h = WHt[f0]; pa_l = WLt[f0]; pb_h = WHt[f1]; pb_l = WLt[f1];
            int g0 = (mt0 * 4 + kpb) * 64 + lane, g1 = g0 + 256;
            pc_h = WHt[g0]; pc_l = WLt[g0]; pd_h = WHt[g1]; pd_l = WLt[g1];
            bar_lds();          // B6: L2 reads done; next tile's buffer ready
        }
    }
}

extern "C" void kernel_launch(void* const* d_in, const int* in_sizes, int n_in,
                              void* d_out, int out_size, void* d_ws, size_t ws_size,
                              hipStream_t stream) {
    const float* img  = (const float*)d_in[0];
    const float* mem  = (const float*)d_in[1];
    const float* pext = (const float*)d_in[2];
    const float* cext = (const float*)d_in[3];
    const int*   midx = (const int*)d_in[4];
    const unsigned char* umem = (const unsigned char*)d_in[5];
    const float* Ws   = (const float*)d_in[6];
    const float* bs   = (const float*)d_in[7];
    float* out = (float*)d_out;
    unsigned char* wsb = (unsigned char*)d_ws;

    hipLaunchKernelGGL(prep, dim3(193), dim3(256), 0, stream,
                       Ws, pext, cext, midx, umem, wsb);
    hipLaunchKernelGGL(fused_main, dim3(NTILES / T_BLK, B_), dim3(512), 0, stream,
                       img, mem, midx, bs, wsb, out);
}

// Round 6
// 163.763 us; speedup vs baseline: 1.2306x; 1.2306x over previous
//
#include <hip/hip_runtime.h>
#include <hip/hip_fp16.h>

#define NC_MEM 64
#define NC_IMG 64
#define NC     128
#define B_     32
#define H_     64
#define W_     96
#define HW_    (H_ * W_)      // 6144
#define P_TILE 128
#define NTILES (HW_ / P_TILE) // 48
#define FS     520            // frag stride in ushorts: 512 + 8 pad
#define FOFF(pt, ks) ((((pt) * 4) + (ks)) * FS)
// rotated block placement (staging-write bank spread, see v4 notes)
#define XOFF(pt, ks, blk) (FOFF(pt, ks) + ((((blk) + (pt)) & 63) << 3))

// d_ws byte layout
#define WA_HI  0                       // ushort[3][8][4][64][8] (f16 hi, A-frag order)
#define WA_LO  98304                   // f16 lo (w - f16(w))
#define XF_OFF 196608                  // float[32][16]
#define UM_OFF 198656                  // float[32]

typedef _Float16 f16x8 __attribute__((ext_vector_type(8)));
typedef __attribute__((ext_vector_type(4))) float f32x4;

__device__ inline unsigned pk2h(float a, float b) {
    __half2 h = __floats2half2_rn(a, b);
    return *(const unsigned*)&h;
}

// LDS-only barrier: orders ds ops across the workgroup WITHOUT draining
// vmcnt. __syncthreads() emits s_waitcnt vmcnt(0) lgkmcnt(0) before
// s_barrier -- it drains every in-flight global load (W prefetches issued
// just before the barrier but consumed after it), exposing L2/L3 latency at
// each of the 5 phase boundaries. v2 (2 blk/CU, 3 bar) == v4 (4 blk/CU,
// 5 bar) == 53 us shows block count / barrier count / bank conflicts are NOT
// the limit; this drain is the remaining structural candidate.
// Correctness: no global->LDS or LDS->global dependence crosses any barrier
// (stage loads are consumed into LDS before B1 via the compiler's own vmcnt
// wait at the pack; output stores happen after all LDS reads). LDS RAW/WAR
// ordering is exactly preserved by lgkmcnt(0)+s_barrier. sched_barrier(0)
// on both flanks pins LDS ops to their side (rule 18).
__device__ inline void bar_lds() {
    __builtin_amdgcn_sched_barrier(0);
    asm volatile("s_waitcnt lgkmcnt(0)" ::: "memory");
    __builtin_amdgcn_s_barrier();
    asm volatile("" ::: "memory");
    __builtin_amdgcn_sched_barrier(0);
}

// ---------------------------------------------------------------------------
// prep: blocks 0..191 split W into f16 hi/lo in MFMA A-fragment order;
// block 192 computes xf via adjugate inverse + decodes use_memory.
// ---------------------------------------------------------------------------
__global__ void prep(const float* __restrict__ Ws,
                     const float* __restrict__ prev_ext,
                     const float* __restrict__ cur_ext,
                     const int* __restrict__ mem_idx,
                     const unsigned char* __restrict__ um_raw,
                     unsigned char* __restrict__ wsb) {
    if (blockIdx.x < 192) {
        int idx = blockIdx.x * 256 + threadIdx.x;   // < 49152 = 3*128*128
        int l = idx >> 14, r = idx & 16383, o = r >> 7, c = r & 127;
        float w = Ws[idx];
        __half hi = __float2half_rn(w);
        __half lo = __float2half_rn(w - __half2float(hi));
        int mt = o >> 4, lm = o & 15, ks = c >> 5, kr = c & 31, q = kr >> 3, j = kr & 7;
        int lane = q * 16 + lm;
        int di = ((((l * 8 + mt) * 4 + ks) * 64 + lane) << 3) + j;
        ((unsigned short*)(wsb + WA_HI))[di] = __half_as_ushort(hi);
        ((unsigned short*)(wsb + WA_LO))[di] = __half_as_ushort(lo);
        return;
    }
    int tb = threadIdx.x;
    if (tb >= 64) return;
    bool flag = (tb < 32) && (tb & 3) && (um_raw[tb] != 0);
    bool is_bool = __any(flag);
    if (tb >= B_) return;
    int b = tb;
    bool um = is_bool ? (um_raw[b] != 0) : (((const int*)um_raw)[b] != 0);
    int mi = mem_idx[b];

    float a[16];
#pragma unroll
    for (int i = 0; i < 16; ++i)
        a[i] = um ? prev_ext[mi * 16 + i] : ((i % 5 == 0) ? 1.f : 0.f);

    float s0 = a[0]*a[5]  - a[1]*a[4];
    float s1 = a[0]*a[6]  - a[2]*a[4];
    float s2 = a[0]*a[7]  - a[3]*a[4];
    float s3 = a[1]*a[6]  - a[2]*a[5];
    float s4 = a[1]*a[7]  - a[3]*a[5];
    float s5 = a[2]*a[7]  - a[3]*a[6];
    float c5 = a[10]*a[15] - a[11]*a[14];
    float c4 = a[9]*a[15]  - a[11]*a[13];
    float c3 = a[9]*a[14]  - a[10]*a[13];
    float c2 = a[8]*a[15]  - a[11]*a[12];
    float c1 = a[8]*a[14]  - a[10]*a[12];
    float c0 = a[8]*a[13]  - a[9]*a[12];
    float det = s0*c5 - s1*c4 + s2*c3 + s3*c2 - s4*c1 + s5*c0;
    float id = 1.0f / det;

    float inv[16];
    inv[0]  = ( a[5]*c5  - a[6]*c4  + a[7]*c3)  * id;
    inv[1]  = (-a[1]*c5  + a[2]*c4  - a[3]*c3)  * id;
    inv[2]  = ( a[13]*s5 - a[14]*s4 + a[15]*s3) * id;
    inv[3]  = (-a[9]*s5  + a[10]*s4 - a[11]*s3) * id;
    inv[4]  = (-a[4]*c5  + a[6]*c2  - a[7]*c1)  * id;
    inv[5]  = ( a[0]*c5  - a[2]*c2  + a[3]*c1)  * id;
    inv[6]  = (-a[12]*s5 + a[14]*s2 - a[15]*s1) * id;
    inv[7]  = ( a[8]*s5  - a[10]*s2 + a[11]*s1) * id;
    inv[8]  = ( a[4]*c4  - a[5]*c2  + a[7]*c0)  * id;
    inv[9]  = (-a[0]*c4  + a[1]*c2  - a[3]*c0)  * id;
    inv[10] = ( a[12]*s4 - a[13]*s2 + a[15]*s0) * id;
    inv[11] = (-a[8]*s4  + a[9]*s2  - a[11]*s0) * id;
    inv[12] = (-a[4]*c3  + a[5]*c1  - a[6]*c0)  * id;
    inv[13] = ( a[0]*c3  - a[1]*c1  + a[2]*c0)  * id;
    inv[14] = (-a[12]*s3 + a[13]*s1 - a[14]*s0) * id;
    inv[15] = ( a[8]*s3  - a[9]*s1  + a[10]*s0) * id;

    float* xf = (float*)(wsb + XF_OFF) + b * 16;
#pragma unroll
    for (int i = 0; i < 4; ++i)
#pragma unroll
        for (int j2 = 0; j2 < 4; ++j2) {
            float s = 0.f;
#pragma unroll
            for (int k = 0; k < 4; ++k)
                s += cur_ext[b * 16 + i * 4 + k] * inv[k * 4 + j2];
            xf[i * 4 + j2] = s;
        }
    ((float*)(wsb + UM_OFF))[b] = um ? 1.f : 0.f;
}

// ---------------------------------------------------------------------------
// fused_main v6 = v4 (53 us baseline: single 33 KB buffer, 1536 blocks,
// natural 64-VGPR allocation, conflict-reduced staging) + TWO changes:
// 1. bar_lds() instead of __syncthreads(): barriers no longer drain vmcnt,
//    so the cross-barrier W prefetches actually stay in flight (in v4 the
//    drain completed them AT the barrier, serializing the phases).
// 2. B-fragment ds_read addresses precomputed ONCE (4 per-nt pointers,
//    identical across all 3 layers; ks becomes a compile-time offset
//    immediate) -- removes ~5 VALU addr ops per ds_read x 48 reads/wave.
// No new live arrays -> register layout unchanged vs v4 (64 VGPR, no spill).
// ---------------------------------------------------------------------------
__global__ __launch_bounds__(512, 4)
void fused_main(const float* __restrict__ img, const float* __restrict__ mem,
                const int* __restrict__ mem_idx, const float* __restrict__ bs,
                const unsigned char* __restrict__ wsb, float* __restrict__ out) {
    __shared__ unsigned short xh[32 * FS]; // 33280 B -> 4 blocks/CU

    const int t   = threadIdx.x;
    const int b   = blockIdx.y;
    const int hw0 = blockIdx.x * P_TILE;
    const bool umb = ((const float*)(wsb + UM_OFF))[b] != 0.f;
    const int mi  = mem_idx[b];

    const f16x8* __restrict__ WH = (const f16x8*)(wsb + WA_HI);
    const f16x8* __restrict__ WL = (const f16x8*)(wsb + WA_LO);

    const int w    = t >> 6;
    const int lane = t & 63;
    const int wq   = lane >> 4;
    const int lm   = lane & 15;
    const int mt0  = 2 * (w & 3);
    const int nt0  = 4 * (w >> 2);

#define FI(l, mt, ks) (((((l) * 8 + (mt)) * 4) + (ks)) * 64 + lane)

    // ---- stage: global f32 -> (FTL) -> f16 in LDS, rotated frag order ----
    {
        const int q   = ((t & 7) << 2) | ((t >> 3) & 3); // px quad, pt-major lane order
        const int og  = t >> 5;        // 0..15
        const int px0 = hw0 + q * 4;
        const int pt  = q >> 2;        // == t & 7
        if (umb) {
            const int c0 = og * 8;     // 8 channels, all on one side of 64
            const float* basep = (c0 < NC_MEM)
                ? (mem + ((size_t)mi * NC_MEM + c0) * HW_ + px0)
                : (img + ((size_t)b * NC_IMG + (c0 - NC_MEM)) * HW_ + px0);
            f32x4 v[8];
#pragma unroll
            for (int cc = 0; cc < 8; ++cc)
                v[cc] = *(const f32x4*)(basep + (size_t)cc * HW_);
            if (og < 4) {              // FTL on channel groups 0..7 (c < 32)
                float xfv[16];
                const float* xfp = (const float*)(wsb + XF_OFF) + b * 16;
#pragma unroll
                for (int j = 0; j < 4; ++j)
                    *(f32x4*)&xfv[j * 4] = *(const f32x4*)&xfp[j * 4];
#pragma unroll
                for (int sg = 0; sg < 2; ++sg) {
#pragma unroll
                    for (int i = 0; i < 4; ++i) {
                        float a0 = v[4*sg+0][i], a1 = v[4*sg+1][i];
                        float a2 = v[4*sg+2][i], a3 = v[4*sg+3][i];
                        v[4*sg+0][i] = xfv[0]*a0  + xfv[1]*a1  + xfv[2]*a2  + xfv[3]*a3;
                        v[4*sg+1][i] = xfv[4]*a0  + xfv[5]*a1  + xfv[6]*a2  + xfv[7]*a3;
                        v[4*sg+2][i] = xfv[8]*a0  + xfv[9]*a1  + xfv[10]*a2 + xfv[11]*a3;
                        v[4*sg+3][i] = xfv[12]*a0 + xfv[13]*a1 + xfv[14]*a2 + xfv[15]*a3;
                    }
                }
            }
            const int bk0 = (og & 3) * 16 + (q & 3) * 4;
#pragma unroll
            for (int i = 0; i < 4; ++i) {
                uint4 pk;
                pk.x = pk2h(v[0][i], v[1][i]);
                pk.y = pk2h(v[2][i], v[3][i]);
                pk.z = pk2h(v[4][i], v[5][i]);
                pk.w = pk2h(v[6][i], v[7][i]);
                *(uint4*)&xh[XOFF(pt, og >> 2, bk0 + i)] = pk;
            }
        } else {
            // img channels only (groups 16..31); mem half never read (layer 0
            // skips ks 0/1 in this case)
            const int gg = 16 + og;
            const int c0 = gg * 4 - NC_MEM;  // img channel 0..60
            f32x4 u[4];
#pragma unroll
            for (int cc = 0; cc < 4; ++cc)
                u[cc] = *(const f32x4*)(img + ((size_t)b * NC_IMG + c0 + cc) * HW_ + px0);
            const int bk0 = ((gg & 7) >> 1) * 16 + (q & 3) * 4;
            const int hoff = (gg & 1) * 4;
#pragma unroll
            for (int i = 0; i < 4; ++i)
                *(uint2*)&xh[XOFF(pt, gg >> 3, bk0 + i) + hoff] =
                    make_uint2(pk2h(u[0][i], u[1][i]), pk2h(u[2][i], u[3][i]));
        }
    }

    // ---- B-fragment read pointers: computed ONCE, valid for all layers ----
    // byte addr for (nt,ks) = bp[nt] + ks*1040 (compile-time offset imm)
    const unsigned short* bp[4];
#pragma unroll
    for (int nt = 0; nt < 4; ++nt)
        bp[nt] = &xh[XOFF(nt0 + nt, 0, lane)];

    // ---- prefetch layer-0 A frags BEFORE the barrier (they now genuinely
    // stay in flight: bar_lds doesn't drain vmcnt) ----
    const int kpa = umb ? 0 : 2, kpb = umb ? 1 : 3;
    f16x8 p0h = WH[FI(0, mt0,     kpa)], p0l = WL[FI(0, mt0,     kpa)];
    f16x8 p1h = WH[FI(0, mt0 + 1, kpa)], p1l = WL[FI(0, mt0 + 1, kpa)];
    f16x8 p2h = WH[FI(0, mt0,     kpb)], p2l = WL[FI(0, mt0,     kpb)];
    f16x8 p3h = WH[FI(0, mt0 + 1, kpb)], p3l = WL[FI(0, mt0 + 1, kpb)];

    bar_lds();   // B1: stage complete

    f32x4 acc[2][4];

    auto run_ks = [&](int ks, f16x8 ah0, f16x8 al0, f16x8 ah1, f16x8 al1) {
#pragma unroll
        for (int nt = 0; nt < 4; ++nt) {
            f16x8 bh = *(const f16x8*)(bp[nt] + ks * FS);
            acc[0][nt] = __builtin_amdgcn_mfma_f32_16x16x32_f16(ah0, bh, acc[0][nt], 0, 0, 0);
            acc[1][nt] = __builtin_amdgcn_mfma_f32_16x16x32_f16(ah1, bh, acc[1][nt], 0, 0, 0);
            acc[0][nt] = __builtin_amdgcn_mfma_f32_16x16x32_f16(al0, bh, acc[0][nt], 0, 0, 0);
            acc[1][nt] = __builtin_amdgcn_mfma_f32_16x16x32_f16(al1, bh, acc[1][nt], 0, 0, 0);
        }
    };
    auto writeback = [&]() {
#pragma unroll
        for (int mi2 = 0; mi2 < 2; ++mi2) {
            const int mt = mt0 + mi2;
            const int ks2 = mt >> 1;
            const int lane_f = ((mt & 1) * 2 + (wq >> 1)) * 16 + lm;
            const int j0 = (wq & 1) * 4;
#pragma unroll
            for (int nt = 0; nt < 4; ++nt) {
                float v0 = fmaxf(acc[mi2][nt][0], 0.f);
                float v1 = fmaxf(acc[mi2][nt][1], 0.f);
                float v2 = fmaxf(acc[mi2][nt][2], 0.f);
                float v3 = fmaxf(acc[mi2][nt][3], 0.f);
                *(uint2*)&xh[XOFF(nt0 + nt, ks2, lane_f) + j0] =
                    make_uint2(pk2h(v0, v1), pk2h(v2, v3));
            }
        }
    };

    // ---------------- layer 0 ----------------
#pragma unroll
    for (int mi2 = 0; mi2 < 2; ++mi2) {
        f32x4 bv = *(const f32x4*)&bs[0 * NC + (mt0 + mi2) * 16 + wq * 4];
#pragma unroll
        for (int nt = 0; nt < 4; ++nt) acc[mi2][nt] = bv;
    }
    __builtin_amdgcn_s_setprio(1);
    if (umb) {
        run_ks(0, p0h, p0l, p1h, p1l);
        run_ks(1, p2h, p2l, p3h, p3l);
        run_ks(2, WH[FI(0, mt0, 2)], WL[FI(0, mt0, 2)],
                  WH[FI(0, mt0 + 1, 2)], WL[FI(0, mt0 + 1, 2)]);
        run_ks(3, WH[FI(0, mt0, 3)], WL[FI(0, mt0, 3)],
                  WH[FI(0, mt0 + 1, 3)], WL[FI(0, mt0 + 1, 3)]);
    } else {
        run_ks(2, p0h, p0l, p1h, p1l);
        run_ks(3, p2h, p2l, p3h, p3l);
    }
    __builtin_amdgcn_s_setprio(0);
    // prefetch layer-1 ks0/ks1 across the barriers (p* regs are dead now;
    // these loads stay in flight through B2/B3)
    f16x8 q0h = WH[FI(1, mt0, 0)],     q0l = WL[FI(1, mt0, 0)];
    f16x8 q1h = WH[FI(1, mt0 + 1, 0)], q1l = WL[FI(1, mt0 + 1, 0)];
    f16x8 q2h = WH[FI(1, mt0, 1)],     q2l = WL[FI(1, mt0, 1)];
    f16x8 q3h = WH[FI(1, mt0 + 1, 1)], q3l = WL[FI(1, mt0 + 1, 1)];
    bar_lds();              // B2: all layer-0 reads of xh done
    writeback();            // overwrite xh in place
    bar_lds();              // B3: layer-0 output visible

    // ---------------- layer 1 ----------------
#pragma unroll
    for (int mi2 = 0; mi2 < 2; ++mi2) {
        f32x4 bv = *(const f32x4*)&bs[1 * NC + (mt0 + mi2) * 16 + wq * 4];
#pragma unroll
        for (int nt = 0; nt < 4; ++nt) acc[mi2][nt] = bv;
    }
    __builtin_amdgcn_s_setprio(1);
    run_ks(0, q0h, q0l, q1h, q1l);
    run_ks(1, q2h, q2l, q3h, q3l);
    run_ks(2, WH[FI(1, mt0, 2)], WL[FI(1, mt0, 2)],
              WH[FI(1, mt0 + 1, 2)], WL[FI(1, mt0 + 1, 2)]);
    run_ks(3, WH[FI(1, mt0, 3)], WL[FI(1, mt0, 3)],
              WH[FI(1, mt0 + 1, 3)], WL[FI(1, mt0 + 1, 3)]);
    __builtin_amdgcn_s_setprio(0);
    // prefetch ALL layer-2 A frags (single mt per wave -> 8 frags); they
    // stay in flight through B4/B5
    const int mt2 = 4 + (w & 3);
    f16x8 r0h = WH[FI(2, mt2, 0)], r0l = WL[FI(2, mt2, 0)];
    f16x8 r1h = WH[FI(2, mt2, 1)], r1l = WL[FI(2, mt2, 1)];
    f16x8 r2h = WH[FI(2, mt2, 2)], r2l = WL[FI(2, mt2, 2)];
    f16x8 r3h = WH[FI(2, mt2, 3)], r3l = WL[FI(2, mt2, 3)];
    bar_lds();              // B4: all layer-1 reads of xh done
    writeback();
    bar_lds();              // B5: layer-1 output visible

    // ---------------- layer 2: out channels 64..127 only ----------------
    {
        f32x4 a2[4];
        f32x4 bv = *(const f32x4*)&bs[2 * NC + mt2 * 16 + wq * 4];
#pragma unroll
        for (int nt = 0; nt < 4; ++nt) a2[nt] = bv;
        auto run2 = [&](int ks, f16x8 ah, f16x8 al) {
#pragma unroll
            for (int nt = 0; nt < 4; ++nt) {
                f16x8 bh = *(const f16x8*)(bp[nt] + ks * FS);
                a2[nt] = __builtin_amdgcn_mfma_f32_16x16x32_f16(ah, bh, a2[nt], 0, 0, 0);
                a2[nt] = __builtin_amdgcn_mfma_f32_16x16x32_f16(al, bh, a2[nt], 0, 0, 0);
            }
        };
        __builtin_amdgcn_s_setprio(1);
        run2(0, r0h, r0l);
        run2(1, r1h, r1l);
        run2(2, r2h, r2l);
        run2(3, r3h, r3l);
        __builtin_amdgcn_s_setprio(0);
        const int oc0 = mt2 * 16 + wq * 4 - 64; // 0..63
#pragma unroll
        for (int nt = 0; nt < 4; ++nt) {
            float* dst = out + ((size_t)b * 64 + oc0) * HW_ + hw0 + (nt0 + nt) * 16 + lm;
#pragma unroll
            for (int r = 0; r < 4; ++r)
                __builtin_nontemporal_store(a2[nt][r], dst + (size_t)r * HW_);
        }
    }
#undef FI
}

extern "C" void kernel_launch(void* const* d_in, const int* in_sizes, int n_in,
                              void* d_out, int out_size, void* d_ws, size_t ws_size,
                              hipStream_t stream) {
    const float* img  = (const float*)d_in[0];
    const float* mem  = (const float*)d_in[1];
    const float* pext = (const float*)d_in[2];
    const float* cext = (const float*)d_in[3];
    const int*   midx = (const int*)d_in[4];
    const unsigned char* umem = (const unsigned char*)d_in[5];
    const float* Ws   = (const float*)d_in[6];
    const float* bs   = (const float*)d_in[7];
    float* out = (float*)d_out;
    unsigned char* wsb = (unsigned char*)d_ws;

    hipLaunchKernelGGL(prep, dim3(193), dim3(256), 0, stream,
                       Ws, pext, cext, midx, umem, wsb);
    hipLaunchKernelGGL(fused_main, dim3(NTILES, B_), dim3(512), 0, stream,
                       img, mem, midx, bs, wsb, out);
}